// Round 10
// baseline (141.485 us; speedup 1.0000x reference)
//
#include <hip/hip_runtime.h>
#include <hip/hip_bf16.h>

typedef __hip_bfloat16 bf16;

__device__ __forceinline__ float b2f(unsigned short u) {
    union { unsigned int i; float f; } v;
    v.i = ((unsigned int)u) << 16;
    return v.f;
}

// ---------------------------------------------------------------------------
// Inputs FP32, OUTPUT FP32 (reference output dtype is float32 — previous
// rounds wrote bf16 into the fp32 buffer: packed halves + 2 MB of zeros,
// which exactly reproduced the observed 0.703125 / NaN signatures).
//
// Kernel 1: prep. For each row r (b,n flattened, 2048 rows):
//   A'[r][k] = b1c[k] + sum_d X[r][d] * W1c[d][k]    -> d_ws bf16 [0,512KB)
//   B [r][k] =          sum_d X[r][d] * W1c[128+d][k] -> d_ws bf16 [512KB,1MB)
//   out[b][i][i] = sigmoid(relu(X·W1s + b1s)·W2s + b2s)   (fp32 store)
// ---------------------------------------------------------------------------
__global__ __launch_bounds__(256) void prep_kernel(
    const float* __restrict__ X,   const float* __restrict__ W1c,
    const float* __restrict__ b1c, const float* __restrict__ W1s,
    const float* __restrict__ b1s, const float* __restrict__ W2s,
    const float* __restrict__ b2s,
    bf16* __restrict__ Aws, bf16* __restrict__ Bws,
    float* __restrict__ out)
{
    __shared__ float Xl[8 * 128];
    __shared__ float dpart[4][4];

    const int t = threadIdx.x;
    const int row0 = blockIdx.x * 8;

    ((float4*)Xl)[t] = ((const float4*)(X + row0 * 128))[t];
    __syncthreads();

    const int k  = t & 127;
    const int hf = t >> 7;

    float accA[4], accB[4], accS[4];
    const float biasA = b1c[k];
    const float biasS = b1s[k];
#pragma unroll
    for (int r = 0; r < 4; ++r) { accA[r] = biasA; accB[r] = 0.f; accS[r] = biasS; }

    const float* WA = W1c + k;
    const float* WB = W1c + 128 * 128 + k;
    const float* WS = W1s + k;
    const float* xbase = Xl + hf * 4 * 128;

    for (int d = 0; d < 128; d += 4) {
        float xv[4][4];
#pragma unroll
        for (int r = 0; r < 4; ++r) {
            float4 q = *(const float4*)(xbase + r * 128 + d);
            xv[r][0] = q.x; xv[r][1] = q.y; xv[r][2] = q.z; xv[r][3] = q.w;
        }
#pragma unroll
        for (int e = 0; e < 4; ++e) {
            const float wa = WA[(d + e) * 128];
            const float wb = WB[(d + e) * 128];
            const float ws = WS[(d + e) * 128];
#pragma unroll
            for (int r = 0; r < 4; ++r) {
                accA[r] += xv[r][e] * wa;
                accB[r] += xv[r][e] * wb;
                accS[r] += xv[r][e] * ws;
            }
        }
    }

#pragma unroll
    for (int r = 0; r < 4; ++r) {
        const int row = row0 + hf * 4 + r;
        Aws[row * 128 + k] = __float2bfloat16(accA[r]);
        Bws[row * 128 + k] = __float2bfloat16(accB[r]);
    }

    const float w2 = W2s[k];
    float p[4];
#pragma unroll
    for (int r = 0; r < 4; ++r) p[r] = fmaxf(accS[r], 0.f) * w2;
#pragma unroll
    for (int off = 32; off; off >>= 1) {
#pragma unroll
        for (int r = 0; r < 4; ++r) p[r] += __shfl_xor(p[r], off, 64);
    }
    const int lane = t & 63, wv = t >> 6;
    if (lane == 0) {
#pragma unroll
        for (int r = 0; r < 4; ++r) dpart[wv][r] = p[r];
    }
    __syncthreads();
    if (t < 8) {
        const int h2 = t >> 2, r = t & 3;
        const float val = dpart[h2 * 2][r] + dpart[h2 * 2 + 1][r] + b2s[0];
        const float sg = 1.f / (1.f + __expf(-val));
        const int rr = row0 + h2 * 4 + r;
        const int bb = rr >> 9, ii = rr & 511;
        out[(size_t)bb * 512 * 512 + (size_t)ii * 512 + ii] = sg;
    }
}

// ---------------------------------------------------------------------------
// Kernel 2: pair — zero LDS. Grid 256 = b(4) x bi(8) x bj(8) tiles of 64x64,
// 256 threads, 4x4 micro-tile per thread. FP32 stores.
//   i<j : sigmoid(w2c . relu(A'[i] + B[j]) + b2c)
//   i>j : mirror -> relu(A'[j] + B[i]) via swapped operand bases
//   i==j: skipped (prep wrote the true diagonal)
// ---------------------------------------------------------------------------
__global__ __launch_bounds__(256) void pair_kernel(
    const bf16* __restrict__ Awsb, const bf16* __restrict__ Bwsb,
    const float* __restrict__ W2c, const float* __restrict__ b2c,
    float* __restrict__ out)
{
    const ushort* Aws = (const ushort*)Awsb;
    const ushort* Bws = (const ushort*)Bwsb;

    const int t   = threadIdx.x;
    const int b   = blockIdx.x >> 6;
    const int rem = blockIdx.x & 63;
    const int bi  = rem >> 3;
    const int bj  = rem & 7;
    const bool isdiag = (bi == bj);
    const bool upper  = (bi <= bj);

    const ushort* lhsg = (upper ? Aws : Bws) + (size_t)(b * 512 + bi * 64) * 128;
    const ushort* rhsg = (upper ? Bws : Aws) + (size_t)(b * 512 + bj * 64) * 128;

    const int tx = t & 15;
    const int ty = t >> 4;

    float acc[4][4], accl[4][4];
#pragma unroll
    for (int r = 0; r < 4; ++r)
#pragma unroll
        for (int s = 0; s < 4; ++s) { acc[r][s] = 0.f; accl[r][s] = 0.f; }

    for (int kk = 0; kk < 128; kk += 4) {
        float4 w4 = *(const float4*)(W2c + kk);       // wave-uniform
        float wv[4] = {w4.x, w4.y, w4.z, w4.w};

        float av[4][4], bv[4][4];
#pragma unroll
        for (int r = 0; r < 4; ++r) {
            ushort4 u = *(const ushort4*)(lhsg + (ty + 16 * r) * 128 + kk);
            av[r][0] = b2f(u.x); av[r][1] = b2f(u.y);
            av[r][2] = b2f(u.z); av[r][3] = b2f(u.w);
        }
#pragma unroll
        for (int s = 0; s < 4; ++s) {
            ushort4 u = *(const ushort4*)(rhsg + (tx + 16 * s) * 128 + kk);
            bv[s][0] = b2f(u.x); bv[s][1] = b2f(u.y);
            bv[s][2] = b2f(u.z); bv[s][3] = b2f(u.w);
        }
#pragma unroll
        for (int e = 0; e < 4; ++e)
#pragma unroll
            for (int r = 0; r < 4; ++r)
#pragma unroll
                for (int s = 0; s < 4; ++s)
                    acc[r][s] += fmaxf(av[r][e] + bv[s][e], 0.f) * wv[e];

        if (isdiag) {
            float av2[4][4], bv2[4][4];
#pragma unroll
            for (int s = 0; s < 4; ++s) {
                ushort4 u = *(const ushort4*)(lhsg + (tx + 16 * s) * 128 + kk);
                av2[s][0] = b2f(u.x); av2[s][1] = b2f(u.y);
                av2[s][2] = b2f(u.z); av2[s][3] = b2f(u.w);
            }
#pragma unroll
            for (int r = 0; r < 4; ++r) {
                ushort4 u = *(const ushort4*)(rhsg + (ty + 16 * r) * 128 + kk);
                bv2[r][0] = b2f(u.x); bv2[r][1] = b2f(u.y);
                bv2[r][2] = b2f(u.z); bv2[r][3] = b2f(u.w);
            }
#pragma unroll
            for (int e = 0; e < 4; ++e)
#pragma unroll
                for (int r = 0; r < 4; ++r)
#pragma unroll
                    for (int s = 0; s < 4; ++s)
                        accl[r][s] += fmaxf(av2[s][e] + bv2[r][e], 0.f) * wv[e];
        }
    }

    const float bias2 = b2c[0];
    float* outb = out + ((size_t)b << 18);

    if (!isdiag) {
#pragma unroll
        for (int r = 0; r < 4; ++r) {
            const int i = bi * 64 + ty + 16 * r;
#pragma unroll
            for (int s = 0; s < 4; ++s) {
                const int j = bj * 64 + tx + 16 * s;
                outb[i * 512 + j] = 1.f / (1.f + __expf(-(acc[r][s] + bias2)));
            }
        }
    } else {
#pragma unroll
        for (int r = 0; r < 4; ++r) {
            const int li = ty + 16 * r;
            const int i  = bi * 64 + li;
#pragma unroll
            for (int s = 0; s < 4; ++s) {
                const int lj = tx + 16 * s;
                const int j  = bj * 64 + lj;
                if (li < lj)
                    outb[i * 512 + j] = 1.f / (1.f + __expf(-(acc[r][s] + bias2)));
                else if (li > lj)
                    outb[i * 512 + j] = 1.f / (1.f + __expf(-(accl[r][s] + bias2)));
                // li == lj: true diagonal written by prep_kernel
            }
        }
    }
}

// ---------------------------------------------------------------------------
extern "C" void kernel_launch(void* const* d_in, const int* in_sizes, int n_in,
                              void* d_out, int out_size, void* d_ws, size_t ws_size,
                              hipStream_t stream) {
    const float* X   = (const float*)d_in[0];
    const float* W1c = (const float*)d_in[1];
    const float* b1c = (const float*)d_in[2];
    const float* W2c = (const float*)d_in[3];
    const float* b2c = (const float*)d_in[4];
    const float* W1s = (const float*)d_in[5];
    const float* b1s = (const float*)d_in[6];
    const float* W2s = (const float*)d_in[7];
    const float* b2s = (const float*)d_in[8];

    bf16* Aws = (bf16*)d_ws;                   // [2048][128] bf16  (512 KB)
    bf16* Bws = Aws + 2048 * 128;              // [2048][128] bf16  (512 KB)

    float* out = (float*)d_out;                // [4][512][512] fp32

    prep_kernel<<<256, 256, 0, stream>>>(X, W1c, b1c, W1s, b1s, W2s, b2s,
                                         Aws, Bws, out);
    pair_kernel<<<256, 256, 0, stream>>>(Aws, Bws, W2c, b2c, out);
}

// Round 11
// 121.318 us; speedup vs baseline: 1.1662x; 1.1662x over previous
//
#include <hip/hip_runtime.h>
#include <hip/hip_bf16.h>

typedef __hip_bfloat16 bf16;

__device__ __forceinline__ float lo2f(unsigned int w) {
    union { unsigned int i; float f; } v; v.i = w << 16; return v.f;
}
__device__ __forceinline__ float hi2f(unsigned int w) {
    union { unsigned int i; float f; } v; v.i = w & 0xFFFF0000u; return v.f;
}

// ---------------------------------------------------------------------------
// Inputs FP32, OUTPUT FP32.
//
// Kernel 1: prep. Grid 1024 x 256 (2 rows/block -> 4 blocks/CU, 16 waves/CU;
// the 8-rows/256-blocks version was latency-bound at 1 block/CU).
// For row r: A'[r][k] = b1c[k] + X[r]·W1c[0:128,k]   -> d_ws bf16 [0,512KB)
//            B [r][k] =          X[r]·W1c[128:256,k] -> d_ws bf16 [512KB,1MB)
//            out[b][i][i] = sigmoid(relu(X·W1s+b1s)·W2s + b2s)
// Thread t: k = t&127, hf = t>>7 selects the row.
// ---------------------------------------------------------------------------
__global__ __launch_bounds__(256) void prep_kernel(
    const float* __restrict__ X,   const float* __restrict__ W1c,
    const float* __restrict__ b1c, const float* __restrict__ W1s,
    const float* __restrict__ b1s, const float* __restrict__ W2s,
    const float* __restrict__ b2s,
    bf16* __restrict__ Aws, bf16* __restrict__ Bws,
    float* __restrict__ out)
{
    __shared__ float Xl[2 * 128];
    __shared__ float dpart[4];

    const int t = threadIdx.x;
    const int row0 = blockIdx.x * 2;

    if (t < 64) ((float4*)Xl)[t] = ((const float4*)(X + row0 * 128))[t];
    __syncthreads();

    const int k  = t & 127;
    const int hf = t >> 7;

    float accA = b1c[k], accB = 0.f, accS = b1s[k];

    const float* WA = W1c + k;
    const float* WB = W1c + 128 * 128 + k;
    const float* WS = W1s + k;
    const float* xbase = Xl + hf * 128;

    for (int d = 0; d < 128; d += 4) {
        float4 q = *(const float4*)(xbase + d);
        float xs[4] = {q.x, q.y, q.z, q.w};
#pragma unroll
        for (int e = 0; e < 4; ++e) {
            accA += xs[e] * WA[(d + e) * 128];
            accB += xs[e] * WB[(d + e) * 128];
            accS += xs[e] * WS[(d + e) * 128];
        }
    }

    const int row = row0 + hf;
    Aws[row * 128 + k] = __float2bfloat16(accA);
    Bws[row * 128 + k] = __float2bfloat16(accB);

    // diag: reduce relu(accS)*W2s[k] over the 128 k's of this row (2 waves)
    float p = fmaxf(accS, 0.f) * W2s[k];
#pragma unroll
    for (int off = 32; off; off >>= 1) p += __shfl_xor(p, off, 64);
    const int wv = t >> 6;
    if ((t & 63) == 0) dpart[wv] = p;
    __syncthreads();
    if (t < 2) {
        const float val = dpart[t * 2] + dpart[t * 2 + 1] + b2s[0];
        const float sg = 1.f / (1.f + __expf(-val));
        const int rr = row0 + t;
        const int bb = rr >> 9, ii = rr & 511;
        out[(size_t)bb * 512 * 512 + (size_t)ii * 512 + ii] = sg;
    }
}

// ---------------------------------------------------------------------------
// Kernel 2: pair — zero LDS. Grid 1024 = b(4) x bi(16) x bj(16) tiles of
// 32x32 (4 blocks/CU, 16 waves/CU), 256 threads, 2x2 micro-tile per thread
// (rows ty+16r, cols tx+16s). 16B uint4 operand loads, 8-k chunks.
//   i<j : sigmoid(w2c . relu(A'[i] + B[j]) + b2c)
//   i>j : mirror -> relu(A'[j] + B[i]) via swapped operand bases
//   i==j: skipped (prep wrote the true diagonal)
// ---------------------------------------------------------------------------
__global__ __launch_bounds__(256) void pair_kernel(
    const bf16* __restrict__ Awsb, const bf16* __restrict__ Bwsb,
    const float* __restrict__ W2c, const float* __restrict__ b2c,
    float* __restrict__ out)
{
    const unsigned int* Aws = (const unsigned int*)Awsb;   // packed bf16 pairs
    const unsigned int* Bws = (const unsigned int*)Bwsb;

    const int t   = threadIdx.x;
    const int b   = blockIdx.x >> 8;
    const int rem = blockIdx.x & 255;
    const int bi  = rem >> 4;
    const int bj  = rem & 15;
    const bool isdiag = (bi == bj);
    const bool upper  = (bi <= bj);

    // row stride in uints: 128 bf16 = 64 uints
    const unsigned int* lhsg = (upper ? Aws : Bws) + (size_t)(b * 512 + bi * 32) * 64;
    const unsigned int* rhsg = (upper ? Bws : Aws) + (size_t)(b * 512 + bj * 32) * 64;

    const int tx = t & 15;
    const int ty = t >> 4;

    float acc[2][2]  = {{0.f, 0.f}, {0.f, 0.f}};
    float accl[2][2] = {{0.f, 0.f}, {0.f, 0.f}};

    for (int kk = 0; kk < 128; kk += 8) {       // 8 bf16 = 4 uints = 16 B
        const int cu = kk >> 1;                 // uint offset within row

        float4 wq0 = *(const float4*)(W2c + kk);
        float4 wq1 = *(const float4*)(W2c + kk + 4);
        float wv[8] = {wq0.x, wq0.y, wq0.z, wq0.w, wq1.x, wq1.y, wq1.z, wq1.w};

        float av[2][8], bv[2][8];
#pragma unroll
        for (int r = 0; r < 2; ++r) {
            uint4 u = *(const uint4*)(lhsg + (ty + 16 * r) * 64 + cu);
            av[r][0] = lo2f(u.x); av[r][1] = hi2f(u.x);
            av[r][2] = lo2f(u.y); av[r][3] = hi2f(u.y);
            av[r][4] = lo2f(u.z); av[r][5] = hi2f(u.z);
            av[r][6] = lo2f(u.w); av[r][7] = hi2f(u.w);
        }
#pragma unroll
        for (int s = 0; s < 2; ++s) {
            uint4 u = *(const uint4*)(rhsg + (tx + 16 * s) * 64 + cu);
            bv[s][0] = lo2f(u.x); bv[s][1] = hi2f(u.x);
            bv[s][2] = lo2f(u.y); bv[s][3] = hi2f(u.y);
            bv[s][4] = lo2f(u.z); bv[s][5] = hi2f(u.z);
            bv[s][6] = lo2f(u.w); bv[s][7] = hi2f(u.w);
        }
#pragma unroll
        for (int e = 0; e < 8; ++e)
#pragma unroll
            for (int r = 0; r < 2; ++r)
#pragma unroll
                for (int s = 0; s < 2; ++s)
                    acc[r][s] += fmaxf(av[r][e] + bv[s][e], 0.f) * wv[e];

        if (isdiag) {
            float av2[2][8], bv2[2][8];
#pragma unroll
            for (int s = 0; s < 2; ++s) {
                uint4 u = *(const uint4*)(lhsg + (tx + 16 * s) * 64 + cu);
                av2[s][0] = lo2f(u.x); av2[s][1] = hi2f(u.x);
                av2[s][2] = lo2f(u.y); av2[s][3] = hi2f(u.y);
                av2[s][4] = lo2f(u.z); av2[s][5] = hi2f(u.z);
                av2[s][6] = lo2f(u.w); av2[s][7] = hi2f(u.w);
            }
#pragma unroll
            for (int r = 0; r < 2; ++r) {
                uint4 u = *(const uint4*)(rhsg + (ty + 16 * r) * 64 + cu);
                bv2[r][0] = lo2f(u.x); bv2[r][1] = hi2f(u.x);
                bv2[r][2] = lo2f(u.y); bv2[r][3] = hi2f(u.y);
                bv2[r][4] = lo2f(u.z); bv2[r][5] = hi2f(u.z);
                bv2[r][6] = lo2f(u.w); bv2[r][7] = hi2f(u.w);
            }
#pragma unroll
            for (int e = 0; e < 8; ++e)
#pragma unroll
                for (int r = 0; r < 2; ++r)
#pragma unroll
                    for (int s = 0; s < 2; ++s)
                        accl[r][s] += fmaxf(av2[s][e] + bv2[r][e], 0.f) * wv[e];
        }
    }

    const float bias2 = b2c[0];
    float* outb = out + ((size_t)b << 18);

    if (!isdiag) {
#pragma unroll
        for (int r = 0; r < 2; ++r) {
            const int i = bi * 32 + ty + 16 * r;
#pragma unroll
            for (int s = 0; s < 2; ++s) {
                const int j = bj * 32 + tx + 16 * s;
                outb[i * 512 + j] = 1.f / (1.f + __expf(-(acc[r][s] + bias2)));
            }
        }
    } else {
#pragma unroll
        for (int r = 0; r < 2; ++r) {
            const int li = ty + 16 * r;
            const int i  = bi * 32 + li;
#pragma unroll
            for (int s = 0; s < 2; ++s) {
                const int lj = tx + 16 * s;
                const int j  = bj * 32 + lj;
                if (li < lj)
                    outb[i * 512 + j] = 1.f / (1.f + __expf(-(acc[r][s] + bias2)));
                else if (li > lj)
                    outb[i * 512 + j] = 1.f / (1.f + __expf(-(accl[r][s] + bias2)));
                // li == lj: true diagonal written by prep_kernel
            }
        }
    }
}

// ---------------------------------------------------------------------------
extern "C" void kernel_launch(void* const* d_in, const int* in_sizes, int n_in,
                              void* d_out, int out_size, void* d_ws, size_t ws_size,
                              hipStream_t stream) {
    const float* X   = (const float*)d_in[0];
    const float* W1c = (const float*)d_in[1];
    const float* b1c = (const float*)d_in[2];
    const float* W2c = (const float*)d_in[3];
    const float* b2c = (const float*)d_in[4];
    const float* W1s = (const float*)d_in[5];
    const float* b1s = (const float*)d_in[6];
    const float* W2s = (const float*)d_in[7];
    const float* b2s = (const float*)d_in[8];

    bf16* Aws = (bf16*)d_ws;                   // [2048][128] bf16  (512 KB)
    bf16* Bws = Aws + 2048 * 128;              // [2048][128] bf16  (512 KB)

    float* out = (float*)d_out;                // [4][512][512] fp32

    prep_kernel<<<1024, 256, 0, stream>>>(X, W1c, b1c, W1s, b1s, W2s, b2s,
                                          Aws, Bws, out);
    pair_kernel<<<1024, 256, 0, stream>>>(Aws, Bws, W2c, b2c, out);
}

// Round 12
// 98.806 us; speedup vs baseline: 1.4319x; 1.2278x over previous
//
#include <hip/hip_runtime.h>
#include <hip/hip_bf16.h>

typedef __hip_bfloat16 bf16;

__device__ __forceinline__ float lo2f(unsigned int w) {
    union { unsigned int i; float f; } v; v.i = w << 16; return v.f;
}
__device__ __forceinline__ float hi2f(unsigned int w) {
    union { unsigned int i; float f; } v; v.i = w & 0xFFFF0000u; return v.f;
}

// ---------------------------------------------------------------------------
// Kernel 1: prep_gemm — C[2048x384] = X[2048x128]·W[128x384] + bias, where
// W columns = [A: W1c rows 0..127 | B: W1c rows 128..255 | S: W1s].
// Outputs bf16: A' (bias b1c) -> Aws, B (no bias) -> Bws, hs (bias b1s,
// NO relu) -> Hws.  32x32 tiles, grid 768 = 64 Mtiles x 12 Ntiles,
// 256 threads, 2x2 micro-tile, full K=128 staged in LDS (weights loaded
// once per block — the per-thread weight-stream version was load-latency
// bound at ~70 µs).
// ---------------------------------------------------------------------------
__global__ __launch_bounds__(256) void prep_gemm(
    const float* __restrict__ X,   const float* __restrict__ W1c,
    const float* __restrict__ b1c, const float* __restrict__ W1s,
    const float* __restrict__ b1s,
    bf16* __restrict__ Aws, bf16* __restrict__ Bws, bf16* __restrict__ Hws)
{
    __shared__ float Xt[32 * 132];   // Xt[r][k]
    __shared__ float Wt[32 * 132];   // Wt[c][k] (transposed during staging)

    const int t  = threadIdx.x;
    const int mt = blockIdx.x / 12;
    const int nt = blockIdx.x % 12;
    const int row0   = mt * 32;
    const int region = nt >> 2;              // 0=A, 1=B, 2=S
    const int cl0    = (nt & 3) * 32;        // local col in [0,128)

    const float* Wbase = (region == 0) ? W1c
                       : (region == 1) ? (W1c + 128 * 128) : W1s;

    // stage X tile: 32 rows x 128 k
#pragma unroll
    for (int q = 0; q < 4; ++q) {
        const int idx = t + q * 256;          // 0..1023 float4's
        const int r = idx >> 5, k4 = idx & 31;
        float4 v = *(const float4*)(X + (size_t)(row0 + r) * 128 + k4 * 4);
        *(float4*)(Xt + r * 132 + k4 * 4) = v;
    }
    // stage W tile transposed: Wt[c][d] <- W[d][cl0+c]
#pragma unroll
    for (int q = 0; q < 4; ++q) {
        const int idx = t + q * 256;          // 0..1023
        const int d = idx >> 3, c4 = idx & 7;
        float4 v = *(const float4*)(Wbase + (size_t)d * 128 + cl0 + c4 * 4);
        Wt[(c4 * 4 + 0) * 132 + d] = v.x;
        Wt[(c4 * 4 + 1) * 132 + d] = v.y;
        Wt[(c4 * 4 + 2) * 132 + d] = v.z;
        Wt[(c4 * 4 + 3) * 132 + d] = v.w;
    }
    __syncthreads();

    const int tx = t & 15, ty = t >> 4;

    float biasv[2];
#pragma unroll
    for (int s = 0; s < 2; ++s) {
        const int cl = cl0 + tx + 16 * s;
        biasv[s] = (region == 0) ? b1c[cl] : (region == 2) ? b1s[cl] : 0.f;
    }
    float acc[2][2] = {{biasv[0], biasv[1]}, {biasv[0], biasv[1]}};

    for (int k = 0; k < 128; k += 8) {
        float xa[2][8], wb[2][8];
#pragma unroll
        for (int r = 0; r < 2; ++r) {
            const float* p = Xt + (ty + 16 * r) * 132 + k;
            float4 a0 = *(const float4*)p;
            float4 a1 = *(const float4*)(p + 4);
            xa[r][0]=a0.x; xa[r][1]=a0.y; xa[r][2]=a0.z; xa[r][3]=a0.w;
            xa[r][4]=a1.x; xa[r][5]=a1.y; xa[r][6]=a1.z; xa[r][7]=a1.w;
        }
#pragma unroll
        for (int s = 0; s < 2; ++s) {
            const float* p = Wt + (tx + 16 * s) * 132 + k;
            float4 b0 = *(const float4*)p;
            float4 b1 = *(const float4*)(p + 4);
            wb[s][0]=b0.x; wb[s][1]=b0.y; wb[s][2]=b0.z; wb[s][3]=b0.w;
            wb[s][4]=b1.x; wb[s][5]=b1.y; wb[s][6]=b1.z; wb[s][7]=b1.w;
        }
#pragma unroll
        for (int e = 0; e < 8; ++e)
#pragma unroll
            for (int r = 0; r < 2; ++r)
#pragma unroll
                for (int s = 0; s < 2; ++s)
                    acc[r][s] += xa[r][e] * wb[s][e];
    }

    bf16* dst = (region == 0) ? Aws : (region == 1) ? Bws : Hws;
#pragma unroll
    for (int r = 0; r < 2; ++r)
#pragma unroll
        for (int s = 0; s < 2; ++s) {
            const int row = row0 + ty + 16 * r;
            const int cl  = cl0 + tx + 16 * s;
            dst[(size_t)row * 128 + cl] = __float2bfloat16(acc[r][s]);
        }
}

// ---------------------------------------------------------------------------
// Kernel 2: pair — LDS-staged. Grid 1024 = b(4) x bi(16) x bj(16), 32x32
// tiles, 256 threads, 2x2 micro-tile. Operands converted bf16->f32 into LDS
// once per block (kills the 16x redundant L2 reads + per-iter unpack of the
// zero-LDS version). Diagonal blocks also reduce relu(hs)·W2s -> sigmoid
// for the true diagonal.
//   i<j : sigmoid(w2c . relu(A'[i] + B[j]) + b2c)
//   i>j : mirror via swapped operand bases
// ---------------------------------------------------------------------------
__global__ __launch_bounds__(256) void pair_kernel(
    const bf16* __restrict__ Awsb, const bf16* __restrict__ Bwsb,
    const bf16* __restrict__ Hwsb,
    const float* __restrict__ W2c, const float* __restrict__ b2c,
    const float* __restrict__ W2s, const float* __restrict__ b2s,
    float* __restrict__ out)
{
    __shared__ float Lsh[32 * 132];
    __shared__ float Rsh[32 * 132];
    __shared__ float w2l[128];
    __shared__ float w2sl[128];
    __shared__ float dred[32 * 8];

    const unsigned int* Aws = (const unsigned int*)Awsb;  // packed bf16 pairs
    const unsigned int* Bws = (const unsigned int*)Bwsb;

    const int t   = threadIdx.x;
    const int b   = blockIdx.x >> 8;
    const int rem = blockIdx.x & 255;
    const int bi  = rem >> 4;
    const int bj  = rem & 15;
    const bool isdiag = (bi == bj);
    const bool upper  = (bi <= bj);

    const unsigned int* lhsg = (upper ? Aws : Bws) + (size_t)(b * 512 + bi * 32) * 64;
    const unsigned int* rhsg = (upper ? Bws : Aws) + (size_t)(b * 512 + bj * 32) * 64;

    // stage both operand tiles, converting to f32
#pragma unroll
    for (int q = 0; q < 2; ++q) {
        const int idx = t + q * 256;          // 0..511
        const int row = idx >> 4, c4 = idx & 15;
        uint4 ua = *(const uint4*)(lhsg + row * 64 + c4 * 4);
        uint4 ub = *(const uint4*)(rhsg + row * 64 + c4 * 4);
        float* La = Lsh + row * 132 + c4 * 8;
        float* Rb = Rsh + row * 132 + c4 * 8;
        La[0]=lo2f(ua.x); La[1]=hi2f(ua.x); La[2]=lo2f(ua.y); La[3]=hi2f(ua.y);
        La[4]=lo2f(ua.z); La[5]=hi2f(ua.z); La[6]=lo2f(ua.w); La[7]=hi2f(ua.w);
        Rb[0]=lo2f(ub.x); Rb[1]=hi2f(ub.x); Rb[2]=lo2f(ub.y); Rb[3]=hi2f(ub.y);
        Rb[4]=lo2f(ub.z); Rb[5]=hi2f(ub.z); Rb[6]=lo2f(ub.w); Rb[7]=hi2f(ub.w);
    }
    if (t < 128) w2l[t]  = W2c[t];
    else         w2sl[t - 128] = W2s[t - 128];
    __syncthreads();

    const int tx = t & 15, ty = t >> 4;

    float acc[2][2]  = {{0.f, 0.f}, {0.f, 0.f}};
    float accl[2][2] = {{0.f, 0.f}, {0.f, 0.f}};

    for (int k = 0; k < 128; k += 8) {
        float wv[8];
        {
            float4 w0 = *(const float4*)(w2l + k);
            float4 w1 = *(const float4*)(w2l + k + 4);
            wv[0]=w0.x; wv[1]=w0.y; wv[2]=w0.z; wv[3]=w0.w;
            wv[4]=w1.x; wv[5]=w1.y; wv[6]=w1.z; wv[7]=w1.w;
        }
        float av[2][8], bv[2][8];
#pragma unroll
        for (int r = 0; r < 2; ++r) {
            const float* p = Lsh + (ty + 16 * r) * 132 + k;
            float4 a0 = *(const float4*)p; float4 a1 = *(const float4*)(p + 4);
            av[r][0]=a0.x; av[r][1]=a0.y; av[r][2]=a0.z; av[r][3]=a0.w;
            av[r][4]=a1.x; av[r][5]=a1.y; av[r][6]=a1.z; av[r][7]=a1.w;
        }
#pragma unroll
        for (int s = 0; s < 2; ++s) {
            const float* p = Rsh + (tx + 16 * s) * 132 + k;
            float4 b0 = *(const float4*)p; float4 b1 = *(const float4*)(p + 4);
            bv[s][0]=b0.x; bv[s][1]=b0.y; bv[s][2]=b0.z; bv[s][3]=b0.w;
            bv[s][4]=b1.x; bv[s][5]=b1.y; bv[s][6]=b1.z; bv[s][7]=b1.w;
        }
#pragma unroll
        for (int e = 0; e < 8; ++e)
#pragma unroll
            for (int r = 0; r < 2; ++r)
#pragma unroll
                for (int s = 0; s < 2; ++s)
                    acc[r][s] += fmaxf(av[r][e] + bv[s][e], 0.f) * wv[e];

        if (isdiag) {
            float av2[2][8], bv2[2][8];
#pragma unroll
            for (int s = 0; s < 2; ++s) {
                const float* p = Lsh + (tx + 16 * s) * 132 + k;
                float4 a0 = *(const float4*)p; float4 a1 = *(const float4*)(p + 4);
                av2[s][0]=a0.x; av2[s][1]=a0.y; av2[s][2]=a0.z; av2[s][3]=a0.w;
                av2[s][4]=a1.x; av2[s][5]=a1.y; av2[s][6]=a1.z; av2[s][7]=a1.w;
            }
#pragma unroll
            for (int r = 0; r < 2; ++r) {
                const float* p = Rsh + (ty + 16 * r) * 132 + k;
                float4 b0 = *(const float4*)p; float4 b1 = *(const float4*)(p + 4);
                bv2[r][0]=b0.x; bv2[r][1]=b0.y; bv2[r][2]=b0.z; bv2[r][3]=b0.w;
                bv2[r][4]=b1.x; bv2[r][5]=b1.y; bv2[r][6]=b1.z; bv2[r][7]=b1.w;
            }
#pragma unroll
            for (int e = 0; e < 8; ++e)
#pragma unroll
                for (int r = 0; r < 2; ++r)
#pragma unroll
                    for (int s = 0; s < 2; ++s)
                        accl[r][s] += fmaxf(av2[s][e] + bv2[r][e], 0.f) * wv[e];
        }
    }

    const float bias2 = b2c[0];
    float* outb = out + ((size_t)b << 18);

    if (!isdiag) {
#pragma unroll
        for (int r = 0; r < 2; ++r) {
            const int i = bi * 32 + ty + 16 * r;
#pragma unroll
            for (int s = 0; s < 2; ++s) {
                const int j = bj * 32 + tx + 16 * s;
                outb[i * 512 + j] = 1.f / (1.f + __expf(-(acc[r][s] + bias2)));
            }
        }
    } else {
#pragma unroll
        for (int r = 0; r < 2; ++r) {
            const int li = ty + 16 * r;
            const int i  = bi * 32 + li;
#pragma unroll
            for (int s = 0; s < 2; ++s) {
                const int lj = tx + 16 * s;
                const int j  = bj * 32 + lj;
                if (li < lj)
                    outb[i * 512 + j] = 1.f / (1.f + __expf(-(acc[r][s] + bias2)));
                else if (li > lj)
                    outb[i * 512 + j] = 1.f / (1.f + __expf(-(accl[r][s] + bias2)));
            }
        }

        // true diagonal: reduce relu(hs)·W2s for this block's 32 rows
        const unsigned int* hsg = (const unsigned int*)Hwsb
                                + (size_t)(b * 512 + bi * 32) * 64;
        const int row = t >> 3, part = t & 7;
        uint4 h0 = *(const uint4*)(hsg + row * 64 + part * 8);
        uint4 h1 = *(const uint4*)(hsg + row * 64 + part * 8 + 4);
        float hv[16] = {lo2f(h0.x),hi2f(h0.x),lo2f(h0.y),hi2f(h0.y),
                        lo2f(h0.z),hi2f(h0.z),lo2f(h0.w),hi2f(h0.w),
                        lo2f(h1.x),hi2f(h1.x),lo2f(h1.y),hi2f(h1.y),
                        lo2f(h1.z),hi2f(h1.z),lo2f(h1.w),hi2f(h1.w)};
        const int k0 = part * 16;
        float p = 0.f;
#pragma unroll
        for (int e = 0; e < 16; ++e)
            p += fmaxf(hv[e], 0.f) * w2sl[k0 + e];
        dred[row * 8 + part] = p;
        __syncthreads();
        if (t < 32) {
            float ssum = b2s[0];
#pragma unroll
            for (int e = 0; e < 8; ++e) ssum += dred[t * 8 + e];
            const float sg = 1.f / (1.f + __expf(-ssum));
            const int i = bi * 32 + t;
            outb[(size_t)i * 512 + i] = sg;
        }
    }
}

// ---------------------------------------------------------------------------
extern "C" void kernel_launch(void* const* d_in, const int* in_sizes, int n_in,
                              void* d_out, int out_size, void* d_ws, size_t ws_size,
                              hipStream_t stream) {
    const float* X   = (const float*)d_in[0];
    const float* W1c = (const float*)d_in[1];
    const float* b1c = (const float*)d_in[2];
    const float* W2c = (const float*)d_in[3];
    const float* b2c = (const float*)d_in[4];
    const float* W1s = (const float*)d_in[5];
    const float* b1s = (const float*)d_in[6];
    const float* W2s = (const float*)d_in[7];
    const float* b2s = (const float*)d_in[8];

    bf16* Aws = (bf16*)d_ws;                   // [2048][128] bf16 (512 KB)
    bf16* Bws = Aws + 2048 * 128;              // [2048][128] bf16 (512 KB)
    bf16* Hws = Bws + 2048 * 128;              // [2048][128] bf16 (512 KB)

    float* out = (float*)d_out;                // [4][512][512] fp32

    prep_gemm<<<768, 256, 0, stream>>>(X, W1c, b1c, W1s, b1s, Aws, Bws, Hws);
    pair_kernel<<<1024, 256, 0, stream>>>(Aws, Bws, Hws, W2c, b2c, W2s, b2s, out);
}

// Round 13
// 88.582 us; speedup vs baseline: 1.5972x; 1.1154x over previous
//
#include <hip/hip_runtime.h>
#include <hip/hip_bf16.h>

typedef __hip_bfloat16 bf16;

__device__ __forceinline__ float lo2f(unsigned int w) {
    union { unsigned int i; float f; } v; v.i = w << 16; return v.f;
}
__device__ __forceinline__ float hi2f(unsigned int w) {
    union { unsigned int i; float f; } v; v.i = w & 0xFFFF0000u; return v.f;
}

// ---------------------------------------------------------------------------
// Kernel 1: prep_gemm — unchanged from R12 (known-good).
// C[2048x384] = X·[W1c_A | W1c_B | W1s] + bias -> bf16 Aws/Bws/Hws.
// ---------------------------------------------------------------------------
__global__ __launch_bounds__(256) void prep_gemm(
    const float* __restrict__ X,   const float* __restrict__ W1c,
    const float* __restrict__ b1c, const float* __restrict__ W1s,
    const float* __restrict__ b1s,
    bf16* __restrict__ Aws, bf16* __restrict__ Bws, bf16* __restrict__ Hws)
{
    __shared__ float Xt[32 * 132];
    __shared__ float Wt[32 * 132];

    const int t  = threadIdx.x;
    const int mt = blockIdx.x / 12;
    const int nt = blockIdx.x % 12;
    const int row0   = mt * 32;
    const int region = nt >> 2;
    const int cl0    = (nt & 3) * 32;

    const float* Wbase = (region == 0) ? W1c
                       : (region == 1) ? (W1c + 128 * 128) : W1s;

#pragma unroll
    for (int q = 0; q < 4; ++q) {
        const int idx = t + q * 256;
        const int r = idx >> 5, k4 = idx & 31;
        float4 v = *(const float4*)(X + (size_t)(row0 + r) * 128 + k4 * 4);
        *(float4*)(Xt + r * 132 + k4 * 4) = v;
    }
#pragma unroll
    for (int q = 0; q < 4; ++q) {
        const int idx = t + q * 256;
        const int d = idx >> 3, c4 = idx & 7;
        float4 v = *(const float4*)(Wbase + (size_t)d * 128 + cl0 + c4 * 4);
        Wt[(c4 * 4 + 0) * 132 + d] = v.x;
        Wt[(c4 * 4 + 1) * 132 + d] = v.y;
        Wt[(c4 * 4 + 2) * 132 + d] = v.z;
        Wt[(c4 * 4 + 3) * 132 + d] = v.w;
    }
    __syncthreads();

    const int tx = t & 15, ty = t >> 4;

    float biasv[2];
#pragma unroll
    for (int s = 0; s < 2; ++s) {
        const int cl = cl0 + tx + 16 * s;
        biasv[s] = (region == 0) ? b1c[cl] : (region == 2) ? b1s[cl] : 0.f;
    }
    float acc[2][2] = {{biasv[0], biasv[1]}, {biasv[0], biasv[1]}};

    for (int k = 0; k < 128; k += 8) {
        float xa[2][8], wb[2][8];
#pragma unroll
        for (int r = 0; r < 2; ++r) {
            const float* p = Xt + (ty + 16 * r) * 132 + k;
            float4 a0 = *(const float4*)p;
            float4 a1 = *(const float4*)(p + 4);
            xa[r][0]=a0.x; xa[r][1]=a0.y; xa[r][2]=a0.z; xa[r][3]=a0.w;
            xa[r][4]=a1.x; xa[r][5]=a1.y; xa[r][6]=a1.z; xa[r][7]=a1.w;
        }
#pragma unroll
        for (int s = 0; s < 2; ++s) {
            const float* p = Wt + (tx + 16 * s) * 132 + k;
            float4 b0 = *(const float4*)p;
            float4 b1 = *(const float4*)(p + 4);
            wb[s][0]=b0.x; wb[s][1]=b0.y; wb[s][2]=b0.z; wb[s][3]=b0.w;
            wb[s][4]=b1.x; wb[s][5]=b1.y; wb[s][6]=b1.z; wb[s][7]=b1.w;
        }
#pragma unroll
        for (int e = 0; e < 8; ++e)
#pragma unroll
            for (int r = 0; r < 2; ++r)
#pragma unroll
                for (int s = 0; s < 2; ++s)
                    acc[r][s] += xa[r][e] * wb[s][e];
    }

    bf16* dst = (region == 0) ? Aws : (region == 1) ? Bws : Hws;
#pragma unroll
    for (int r = 0; r < 2; ++r)
#pragma unroll
        for (int s = 0; s < 2; ++s) {
            const int row = row0 + ty + 16 * r;
            const int cl  = cl0 + tx + 16 * s;
            dst[(size_t)row * 128 + cl] = __float2bfloat16(acc[r][s]);
        }
}

// ---------------------------------------------------------------------------
// Kernel 2: pair — computes each unordered pair ONCE (grid 544 = 4 x 136
// upper-triangle tile pairs, bi<=bj) and writes both (i,j) and (j,i); the
// old version recomputed the mirror with swapped operands = 2x the FLOPs.
// 32x32 tiles, 256 thr, 2x2 micro; operands staged as PACKED bf16 in LDS
// (half the ds_read traffic, unpack in-loop). Mirror stores coalesced via a
// 32x33 f32 LDS transpose tile. Diag tiles read lower half from T and
// splice the true diagonal (relu(hs)·W2s reduction from Hws).
// ---------------------------------------------------------------------------
__global__ __launch_bounds__(256) void pair_kernel(
    const bf16* __restrict__ Awsb, const bf16* __restrict__ Bwsb,
    const bf16* __restrict__ Hwsb,
    const float* __restrict__ W2c, const float* __restrict__ b2c,
    const float* __restrict__ W2s, const float* __restrict__ b2s,
    float* __restrict__ out)
{
    __shared__ unsigned int Lsh[32 * 68];   // packed bf16 pairs, stride 68
    __shared__ unsigned int Rsh[32 * 68];
    __shared__ float w2l[128];
    __shared__ float w2sl[128];
    __shared__ float dred[32 * 8];
    __shared__ float dg[32];
    __shared__ float T[32 * 33];

    const unsigned int* Aws = (const unsigned int*)Awsb;
    const unsigned int* Bws = (const unsigned int*)Bwsb;

    const int t = threadIdx.x;
    const int b = blockIdx.x / 136;
    const int rr = blockIdx.x % 136;
    int bj = (int)((sqrtf(8.f * rr + 1.f) - 1.f) * 0.5f);
    while ((bj + 1) * (bj + 2) / 2 <= rr) ++bj;
    while (bj * (bj + 1) / 2 > rr) --bj;
    const int bi = rr - bj * (bj + 1) / 2;          // bi <= bj
    const bool isdiag = (bi == bj);

    const unsigned int* lhsg = Aws + (size_t)(b * 512 + bi * 32) * 64;
    const unsigned int* rhsg = Bws + (size_t)(b * 512 + bj * 32) * 64;

    // stage packed tiles: 512 uint4 each, 2 per thread
#pragma unroll
    for (int q = 0; q < 2; ++q) {
        const int idx = t + q * 256;
        const int row = idx >> 4, c4 = idx & 15;
        uint4 ua = ((const uint4*)(lhsg + row * 64))[c4];
        uint4 ub = ((const uint4*)(rhsg + row * 64))[c4];
        *(uint4*)(Lsh + row * 68 + c4 * 4) = ua;
        *(uint4*)(Rsh + row * 68 + c4 * 4) = ub;
    }
    if (t < 128) w2l[t] = W2c[t];
    else         w2sl[t - 128] = W2s[t - 128];
    __syncthreads();

    const int tx = t & 15, ty = t >> 4;

    float acc[2][2] = {{0.f, 0.f}, {0.f, 0.f}};

    for (int kk = 0; kk < 128; kk += 8) {
        const int cu = kk >> 1;
        float wv[8];
        {
            float4 w0 = *(const float4*)(w2l + kk);
            float4 w1 = *(const float4*)(w2l + kk + 4);
            wv[0]=w0.x; wv[1]=w0.y; wv[2]=w0.z; wv[3]=w0.w;
            wv[4]=w1.x; wv[5]=w1.y; wv[6]=w1.z; wv[7]=w1.w;
        }
        float av[2][8], bv[2][8];
#pragma unroll
        for (int r = 0; r < 2; ++r) {
            uint4 u = *(const uint4*)(Lsh + (ty + 16 * r) * 68 + cu);
            av[r][0]=lo2f(u.x); av[r][1]=hi2f(u.x);
            av[r][2]=lo2f(u.y); av[r][3]=hi2f(u.y);
            av[r][4]=lo2f(u.z); av[r][5]=hi2f(u.z);
            av[r][6]=lo2f(u.w); av[r][7]=hi2f(u.w);
        }
#pragma unroll
        for (int s = 0; s < 2; ++s) {
            uint4 u = *(const uint4*)(Rsh + (tx + 16 * s) * 68 + cu);
            bv[s][0]=lo2f(u.x); bv[s][1]=hi2f(u.x);
            bv[s][2]=lo2f(u.y); bv[s][3]=hi2f(u.y);
            bv[s][4]=lo2f(u.z); bv[s][5]=hi2f(u.z);
            bv[s][6]=lo2f(u.w); bv[s][7]=hi2f(u.w);
        }
#pragma unroll
        for (int e = 0; e < 8; ++e)
#pragma unroll
            for (int r = 0; r < 2; ++r)
#pragma unroll
                for (int s = 0; s < 2; ++s)
                    acc[r][s] += fmaxf(av[r][e] + bv[s][e], 0.f) * wv[e];
    }

    const float bias2 = b2c[0];
    float val[2][2];
#pragma unroll
    for (int r = 0; r < 2; ++r)
#pragma unroll
        for (int s = 0; s < 2; ++s)
            val[r][s] = 1.f / (1.f + __expf(-(acc[r][s] + bias2)));

    // write transpose tile (also the mirror source)
#pragma unroll
    for (int r = 0; r < 2; ++r)
#pragma unroll
        for (int s = 0; s < 2; ++s)
            T[(ty + 16 * r) * 33 + (tx + 16 * s)] = val[r][s];

    if (isdiag) {
        // true diagonal: relu(hs)·W2s reduction over this block's 32 rows
        const unsigned int* hsg = (const unsigned int*)Hwsb
                                + (size_t)(b * 512 + bi * 32) * 64;
        const int row = t >> 3, part = t & 7;
        uint4 h0 = *(const uint4*)(hsg + row * 64 + part * 8);
        uint4 h1 = *(const uint4*)(hsg + row * 64 + part * 8 + 4);
        float hv[16] = {lo2f(h0.x),hi2f(h0.x),lo2f(h0.y),hi2f(h0.y),
                        lo2f(h0.z),hi2f(h0.z),lo2f(h0.w),hi2f(h0.w),
                        lo2f(h1.x),hi2f(h1.x),lo2f(h1.y),hi2f(h1.y),
                        lo2f(h1.z),hi2f(h1.z),lo2f(h1.w),hi2f(h1.w)};
        const int k0 = part * 16;
        float p = 0.f;
#pragma unroll
        for (int e = 0; e < 16; ++e)
            p += fmaxf(hv[e], 0.f) * w2sl[k0 + e];
        dred[row * 8 + part] = p;
    }
    __syncthreads();
    if (isdiag) {
        if (t < 32) {
            float ssum = b2s[0];
#pragma unroll
            for (int e = 0; e < 8; ++e) ssum += dred[t * 8 + e];
            dg[t] = 1.f / (1.f + __expf(-ssum));
        }
        __syncthreads();          // block-uniform branch: safe
    }

    float* outb = out + ((size_t)b << 18);

    if (!isdiag) {
        // direct stores (upper tile)
#pragma unroll
        for (int r = 0; r < 2; ++r) {
            const int i = bi * 32 + ty + 16 * r;
#pragma unroll
            for (int s = 0; s < 2; ++s) {
                const int j = bj * 32 + tx + 16 * s;
                outb[i * 512 + j] = val[r][s];
            }
        }
        // mirror stores (lower tile), coalesced via T
#pragma unroll
        for (int r = 0; r < 2; ++r) {
            const int a  = ty + 16 * r;
            const int i2 = bj * 32 + a;
#pragma unroll
            for (int s = 0; s < 2; ++s) {
                const int bb = tx + 16 * s;
                const int j2 = bi * 32 + bb;
                outb[i2 * 512 + j2] = T[bb * 33 + a];
            }
        }
    } else {
#pragma unroll
        for (int r = 0; r < 2; ++r) {
            const int li = ty + 16 * r;
            const int i  = bi * 32 + li;
#pragma unroll
            for (int s = 0; s < 2; ++s) {
                const int lj = tx + 16 * s;
                const int j  = bj * 32 + lj;
                float v;
                if (li < lj)      v = val[r][s];
                else if (li > lj) v = T[lj * 33 + li];
                else              v = dg[li];
                outb[i * 512 + j] = v;
            }
        }
    }
}

// ---------------------------------------------------------------------------
extern "C" void kernel_launch(void* const* d_in, const int* in_sizes, int n_in,
                              void* d_out, int out_size, void* d_ws, size_t ws_size,
                              hipStream_t stream) {
    const float* X   = (const float*)d_in[0];
    const float* W1c = (const float*)d_in[1];
    const float* b1c = (const float*)d_in[2];
    const float* W2c = (const float*)d_in[3];
    const float* b2c = (const float*)d_in[4];
    const float* W1s = (const float*)d_in[5];
    const float* b1s = (const float*)d_in[6];
    const float* W2s = (const float*)d_in[7];
    const float* b2s = (const float*)d_in[8];

    bf16* Aws = (bf16*)d_ws;                   // [2048][128] bf16 (512 KB)
    bf16* Bws = Aws + 2048 * 128;              // [2048][128] bf16 (512 KB)
    bf16* Hws = Bws + 2048 * 128;              // [2048][128] bf16 (512 KB)

    float* out = (float*)d_out;                // [4][512][512] fp32

    prep_gemm<<<768, 256, 0, stream>>>(X, W1c, b1c, W1s, b1s, Aws, Bws, Hws);
    pair_kernel<<<544, 256, 0, stream>>>(Aws, Bws, Hws, W2c, b2c, W2s, b2s, out);
}